// Round 5
// baseline (10468.148 us; speedup 1.0000x reference)
//
#include <hip/hip_runtime.h>
#include <stdint.h>

// ---------------------------------------------------------------------------
// ComplexApproximateBNN, round 5: fence-free persistent cooperative kernel.
// Key idea vs R3 (which regressed): NO __threadfence anywhere. All cross-WG
// data (activations h1..h4, h2 ping/pong, sumsq) moves via agent-scope
// RELAXED atomics (sc0/sc1: write-through stores, cache-bypassing loads) ->
// always coherent at the Infinity-Cache point. Weights/bias/act_ids/h0 use
// normal cached loads and their L2 lines are NEVER invalidated (R3's
// buffer_wbl2/inv per barrier was the 5 GB/dispatch HBM refetch poison).
// Grid barrier: two-level (8 groups x 32 arrivals + root), monotone epochs,
// relaxed atomics only; data ordering from s_waitcnt vmcnt(0) before arrival
// (write-through stores are globally visible once vmcnt-acked).
// Tiling per phase: C[64,2048] = act(concat(A1,A2)[64,4096] @ W^T + b)
//   256 WGs = 64 n-tiles (32 cols) x 4 m-tiles (16 rows); 8 waves split K
//   (waves 0-3 -> A1, 4-7 -> A2, 512 k each); LDS reduce; fused bias/act,
//   fused l2norm (A2-partial scaling + sumsq emission).
// y output layer batched into one GEMM after the persistent kernel (h4
// stored per-step into rotating slots overlaid on dead h0 slices).
// ---------------------------------------------------------------------------

typedef __bf16 bf16;
typedef __attribute__((ext_vector_type(8))) __bf16 bf16x8;
typedef __attribute__((ext_vector_type(4))) float f32x4;

#define BATCH 64
#define TSTEPS 128
#define INDIM 512
#define XDIM 2048
#define OUTDIM 256
#define NWG 256
#define SLOTE ((size_t)BATCH * XDIM)

__device__ __forceinline__ float apply_act(float h, int id) {
  switch (id) {
    case 0: return fmaxf(h, 0.0f);
    case 1: return 1.0f / (1.0f + __expf(-h));
    case 2: return tanhf(h);
    case 3: return h >= 0.0f ? h : 0.1f * h;
    default: {
      const float sc = 1.0507009873554805f;
      const float al = 1.6732632423543772f;
      return h > 0.0f ? sc * h : sc * al * (__expf(h) - 1.0f);
    }
  }
}

__device__ __forceinline__ bf16x8 load_n(const bf16* p) {
  return *(const bf16x8*)p;
}
// coherent (agent-scope, cache-bypassing) 16B load as 2x u64 atomics
__device__ __forceinline__ bf16x8 load_c(const bf16* p) {
  union { unsigned long long q[2]; bf16x8 v; } u;
  u.q[0] = __hip_atomic_load((const unsigned long long*)p, __ATOMIC_RELAXED,
                             __HIP_MEMORY_SCOPE_AGENT);
  u.q[1] = __hip_atomic_load((const unsigned long long*)p + 1, __ATOMIC_RELAXED,
                             __HIP_MEMORY_SCOPE_AGENT);
  return u.v;
}

// two-level grid barrier, monotone epoch bt (1-based). No cache maintenance.
__device__ __forceinline__ void gbar(uint32_t* bar, int wg, uint32_t bt) {
  asm volatile("s_waitcnt vmcnt(0)" ::: "memory");  // write-through stores visible
  __syncthreads();
  if (threadIdx.x == 0) {
    const int g = wg >> 5;  // 32 WGs per group
    uint32_t* grp = bar + g * 32;
    uint32_t* root = bar + 8 * 32;
    uint32_t* eps = bar + 9 * 32 + g * 32;
    uint32_t prev = __hip_atomic_fetch_add(grp, 1u, __ATOMIC_RELAXED,
                                           __HIP_MEMORY_SCOPE_AGENT);
    if (prev == 32u * bt - 1u) {  // last of group
      uint32_t pr = __hip_atomic_fetch_add(root, 1u, __ATOMIC_RELAXED,
                                           __HIP_MEMORY_SCOPE_AGENT);
      if (pr == 8u * bt - 1u) {  // last of all: publish epoch to 8 copies
        for (int i = 0; i < 8; i++)
          __hip_atomic_store(bar + 9 * 32 + i * 32, bt, __ATOMIC_RELAXED,
                             __HIP_MEMORY_SCOPE_AGENT);
        goto done;
      }
    }
    while (__hip_atomic_load(eps, __ATOMIC_RELAXED, __HIP_MEMORY_SCOPE_AGENT) < bt)
      __builtin_amdgcn_s_sleep(2);
  done:;
  }
  __syncthreads();
}

// one phase: this WG computes rows [mrow,mrow+16) x cols [nblk,nblk+32).
// ALL_COH: A1 also coherent (in-kernel-produced). A2 always coherent.
template <bool ALL_COH, bool SCALE_A2, bool EMIT_SS>
__device__ __forceinline__ void phase(
    int nblk, int mrow,
    const bf16* __restrict__ A1, const bf16* __restrict__ A2,
    const bf16* __restrict__ W, const float* __restrict__ bias,
    const int* __restrict__ acts, const float* __restrict__ ss_in,
    float* __restrict__ ss_out, bf16* __restrict__ outb,
    float red[8][16][33]) {
  const int tid = threadIdx.x;
  const int lane = tid & 63;
  const int w = tid >> 6;        // 0..7
  const int l15 = lane & 15;
  const int kb8 = (lane >> 4) * 8;

  const bf16* As = (w >= 4) ? A2 : A1;
  const int koff = (w & 3) * 512;
  const int wk = w * 512;

  const bf16* ap = As + (size_t)(mrow + l15) * 2048 + koff + kb8;
  const bf16* bp0 = W + (size_t)(nblk + l15) * 4096 + wk + kb8;
  const bf16* bp1 = bp0 + (size_t)16 * 4096;

  f32x4 acc0 = {0.f, 0.f, 0.f, 0.f};
  f32x4 acc1 = {0.f, 0.f, 0.f, 0.f};
  if (ALL_COH || w >= 4) {
#pragma unroll
    for (int k = 0; k < 512; k += 32) {
      bf16x8 a = load_c(ap + k);
      bf16x8 b0 = load_n(bp0 + k);
      bf16x8 b1 = load_n(bp1 + k);
      acc0 = __builtin_amdgcn_mfma_f32_16x16x32_bf16(a, b0, acc0, 0, 0, 0);
      acc1 = __builtin_amdgcn_mfma_f32_16x16x32_bf16(a, b1, acc1, 0, 0, 0);
    }
  } else {
#pragma unroll
    for (int k = 0; k < 512; k += 32) {
      bf16x8 a = load_n(ap + k);
      bf16x8 b0 = load_n(bp0 + k);
      bf16x8 b1 = load_n(bp1 + k);
      acc0 = __builtin_amdgcn_mfma_f32_16x16x32_bf16(a, b0, acc0, 0, 0, 0);
      acc1 = __builtin_amdgcn_mfma_f32_16x16x32_bf16(a, b1, acc1, 0, 0, 0);
    }
  }

  const int q4 = lane >> 4;
#pragma unroll
  for (int r = 0; r < 4; r++) red[w][q4 * 4 + r][l15] = acc0[r];
#pragma unroll
  for (int r = 0; r < 4; r++) red[w][q4 * 4 + r][16 + l15] = acc1[r];
  __syncthreads();

  if (tid < 256) {
    const int row = tid >> 4;       // 0..15
    const int c0 = (tid & 15) * 2;  // 0..30
    const int rg = mrow + row;

    float scale = 1.0f;
    if (SCALE_A2) {
      float ssv = __hip_atomic_load(ss_in + rg, __ATOMIC_RELAXED,
                                    __HIP_MEMORY_SCOPE_AGENT);
      scale = 1.0f / fmaxf(sqrtf(ssv), 1e-12f);
    }

    float v[2];
#pragma unroll
    for (int j = 0; j < 2; j++) {
      int c = c0 + j;
      float lo = red[0][row][c] + red[1][row][c] + red[2][row][c] + red[3][row][c];
      float hi = red[4][row][c] + red[5][row][c] + red[6][row][c] + red[7][row][c];
      float pre = (SCALE_A2 ? (lo + scale * hi) : (lo + hi)) + bias[nblk + c];
      v[j] = apply_act(pre, acts[nblk + c]);
    }
    if (EMIT_SS) {
      float ss = v[0] * v[0] + v[1] * v[1];
      ss += __shfl_xor(ss, 1);
      ss += __shfl_xor(ss, 2);
      ss += __shfl_xor(ss, 4);
      ss += __shfl_xor(ss, 8);
      if ((tid & 15) == 0) atomicAdd(ss_out + rg, ss);
    }
    union { bf16 b2[2]; uint32_t u; } pk;
    pk.b2[0] = (bf16)v[0];
    pk.b2[1] = (bf16)v[1];
    __hip_atomic_store((uint32_t*)(outb + (size_t)rg * 2048 + nblk + c0), pk.u,
                       __ATOMIC_RELAXED, __HIP_MEMORY_SCOPE_AGENT);
  }
}

struct Params {
  const bf16* h0;       // [T][B][2048] (also rotating h4 slots, mutable view below)
  bf16* h0m;
  const bf16* whb;      // [4][2048][4096]
  const float* b_h;
  const int* act_ids;
  bf16 *h1, *h2a, *h2b, *h3, *extra;  // extra = h4 slots 0,1
  float *ss_li, *ss_bp;
  uint32_t* bar;
};

__global__ __launch_bounds__(512, 2) void bnn_persistent(Params p) {
  __shared__ float red[8][16][33];
  const int wg = blockIdx.x;
  const int nblk = (wg & 63) * 32;
  const int mrow = (wg >> 6) * 16;
  const size_t wstr = (size_t)XDIM * 2 * XDIM;
  uint32_t bt = 0;

  for (int t = 0; t < TSTEPS; t++) {
    const bf16* h0t = p.h0 + (size_t)t * SLOTE;
    const bf16* slotA = (t < 2) ? (p.extra + (size_t)t * SLOTE)
                                : (p.h0 + (size_t)(t - 2) * SLOTE);
    bf16* slotD = (t + 1 < 2) ? (p.extra + (size_t)(t + 1) * SLOTE)
                              : (p.h0m + (size_t)(t - 1) * SLOTE);
    bf16* h2n = (t & 1) ? p.h2b : p.h2a;
    bf16* h2o = (t & 1) ? p.h2a : p.h2b;

    // A: h1 = act([h0_t, norm(h4_t)] @ W0^T + b0)
    phase<false, true, false>(nblk, mrow, h0t, slotA, p.whb, p.b_h,
                              p.act_ids + XDIM, p.ss_bp + t * BATCH, nullptr,
                              p.h1, red);
    gbar(p.bar, wg, ++bt);
    // B: h2 = act([h1, norm(h2_old)] @ W1^T + b1); emit ss_li[t+1]
    phase<true, true, true>(nblk, mrow, p.h1, h2o, p.whb + wstr, p.b_h + XDIM,
                            p.act_ids + 2 * XDIM, p.ss_li + t * BATCH,
                            p.ss_li + (t + 1) * BATCH, h2n, red);
    gbar(p.bar, wg, ++bt);
    // C: h3 = act([h2, h1] @ W2^T + b2)
    phase<true, false, false>(nblk, mrow, h2n, p.h1, p.whb + 2 * wstr,
                              p.b_h + 2 * XDIM, p.act_ids + 3 * XDIM, nullptr,
                              nullptr, p.h3, red);
    gbar(p.bar, wg, ++bt);
    // D: h4 = act([h3, h2] @ W3^T + b3) -> slot t+1; emit ss_bp[t+1]
    phase<true, false, true>(nblk, mrow, p.h3, h2n, p.whb + 3 * wstr,
                             p.b_h + 3 * XDIM, p.act_ids + 4 * XDIM, nullptr,
                             p.ss_bp + (t + 1) * BATCH, slotD, red);
    gbar(p.bar, wg, ++bt);
  }
}

// h0 precompute: [8192,512]@[512->2048], rows r=b*128+t remapped to [t][b][n]
__global__ __launch_bounds__(256) void h0_gemm(
    const bf16* __restrict__ A, const bf16* __restrict__ W,
    const float* __restrict__ bias, const int* __restrict__ acts,
    bf16* __restrict__ outp) {
  const int tid = threadIdx.x;
  const int lane = tid & 63;
  const int wv = tid >> 6;
  const int wm = (wv & 1) * 32;
  const int wn = (wv >> 1) * 64;
  const int nblk = blockIdx.x * 128;
  const int mblk = blockIdx.y * 64;
  const int l15 = lane & 15;
  const int kb8 = (lane >> 4) * 8;

  f32x4 acc[2][4];
  const f32x4 zero = {0.f, 0.f, 0.f, 0.f};
#pragma unroll
  for (int i = 0; i < 2; i++)
#pragma unroll
    for (int j = 0; j < 4; j++) acc[i][j] = zero;

  for (int kt = 0; kt < INDIM; kt += 32) {
    bf16x8 a[2], b[4];
#pragma unroll
    for (int mt = 0; mt < 2; mt++) {
      int m = mblk + wm + mt * 16 + l15;
      a[mt] = *(const bf16x8*)(A + (size_t)m * INDIM + kt + kb8);
    }
#pragma unroll
    for (int nt = 0; nt < 4; nt++) {
      int n = nblk + wn + nt * 16 + l15;
      b[nt] = *(const bf16x8*)(W + (size_t)n * INDIM + kt + kb8);
    }
#pragma unroll
    for (int mt = 0; mt < 2; mt++)
#pragma unroll
      for (int nt = 0; nt < 4; nt++)
        acc[mt][nt] = __builtin_amdgcn_mfma_f32_16x16x32_bf16(a[mt], b[nt], acc[mt][nt], 0, 0, 0);
  }

#pragma unroll
  for (int mt = 0; mt < 2; mt++) {
#pragma unroll
    for (int nt = 0; nt < 4; nt++) {
      int n = nblk + wn + nt * 16 + l15;
      float bv = bias[n];
      int aid = acts[n];
#pragma unroll
      for (int rr = 0; rr < 4; rr++) {
        int m = wm + mt * 16 + (lane >> 4) * 4 + rr;
        float v = apply_act(acc[mt][nt][rr] + bv, aid);
        int rowg = mblk + m;  // = b*128 + t
        int bb = rowg >> 7;
        int tt = rowg & 127;
        outp[((size_t)tt * BATCH + bb) * XDIM + n] = (bf16)v;
      }
    }
  }
}

// batched output layer: y_t = act(h4slot(t+1) @ Wout^T + bout)
__global__ __launch_bounds__(256) void ybat_gemm(
    const bf16* __restrict__ extra, const bf16* __restrict__ h0,
    const bf16* __restrict__ Wout, const float* __restrict__ bout,
    const int* __restrict__ oact, float* __restrict__ out) {
  const int t = blockIdx.y;
  const int s = t + 1;
  const bf16* A = (s < 2) ? (extra + (size_t)s * SLOTE)
                          : (h0 + (size_t)(s - 2) * SLOTE);
  const int tid = threadIdx.x;
  const int lane = tid & 63;
  const int wv = tid >> 6;
  const int wm = (wv & 1) * 32;
  const int wn = (wv >> 1) * 64;
  const int nblk = blockIdx.x * 128;
  const int l15 = lane & 15;
  const int kb8 = (lane >> 4) * 8;

  f32x4 acc[2][4];
  const f32x4 zero = {0.f, 0.f, 0.f, 0.f};
#pragma unroll
  for (int i = 0; i < 2; i++)
#pragma unroll
    for (int j = 0; j < 4; j++) acc[i][j] = zero;

  for (int kt = 0; kt < XDIM; kt += 32) {
    bf16x8 a[2], b[4];
#pragma unroll
    for (int mt = 0; mt < 2; mt++) {
      int m = wm + mt * 16 + l15;
      a[mt] = *(const bf16x8*)(A + (size_t)m * XDIM + kt + kb8);
    }
#pragma unroll
    for (int nt = 0; nt < 4; nt++) {
      int n = nblk + wn + nt * 16 + l15;
      b[nt] = *(const bf16x8*)(Wout + (size_t)n * XDIM + kt + kb8);
    }
#pragma unroll
    for (int mt = 0; mt < 2; mt++)
#pragma unroll
      for (int nt = 0; nt < 4; nt++)
        acc[mt][nt] = __builtin_amdgcn_mfma_f32_16x16x32_bf16(a[mt], b[nt], acc[mt][nt], 0, 0, 0);
  }

#pragma unroll
  for (int mt = 0; mt < 2; mt++) {
#pragma unroll
    for (int nt = 0; nt < 4; nt++) {
      int n = nblk + wn + nt * 16 + l15;
      float bv = bout[n];
      int aid = oact[n];
#pragma unroll
      for (int rr = 0; rr < 4; rr++) {
        int b = wm + mt * 16 + (lane >> 4) * 4 + rr;
        float v = apply_act(acc[mt][nt][rr] + bv, aid);
        out[((size_t)b * TSTEPS + t) * OUTDIM + n] = v;
      }
    }
  }
}

__global__ __launch_bounds__(256) void cvt_bf16(
    const float* __restrict__ in, bf16* __restrict__ out, int n4) {
  int i = blockIdx.x * 256 + threadIdx.x;
  if (i < n4) {
    float4 v = ((const float4*)in)[i];
    union { bf16 b[4]; unsigned long long u; } pk;
    pk.b[0] = (bf16)v.x;
    pk.b[1] = (bf16)v.y;
    pk.b[2] = (bf16)v.z;
    pk.b[3] = (bf16)v.w;
    ((unsigned long long*)out)[i] = pk.u;
  }
}

__global__ __launch_bounds__(256) void zero32(uint32_t* __restrict__ p, int n) {
  int i = blockIdx.x * 256 + threadIdx.x;
  if (i < n) p[i] = 0u;
}

extern "C" void kernel_launch(void* const* d_in, const int* in_sizes, int n_in,
                              void* d_out, int out_size, void* d_ws, size_t ws_size,
                              hipStream_t stream) {
  const float* x     = (const float*)d_in[0];
  const float* W_in  = (const float*)d_in[1];
  const float* b_in  = (const float*)d_in[2];
  const float* W_h   = (const float*)d_in[3];
  const float* b_h   = (const float*)d_in[4];
  const float* W_out = (const float*)d_in[5];
  const float* b_out = (const float*)d_in[6];
  const int* act_ids = (const int*)d_in[7];
  const int* out_act = (const int*)d_in[8];
  float* out = (float*)d_out;

  char* w = (char*)d_ws;
  bf16* xbf   = (bf16*)w; w += (size_t)BATCH * TSTEPS * INDIM * 2;
  bf16* winb  = (bf16*)w; w += (size_t)XDIM * INDIM * 2;
  bf16* whb   = (bf16*)w; w += (size_t)4 * XDIM * (2 * XDIM) * 2;
  bf16* woutb = (bf16*)w; w += (size_t)OUTDIM * XDIM * 2;
  bf16* h0    = (bf16*)w; w += (size_t)TSTEPS * SLOTE * 2;
  bf16* h1    = (bf16*)w; w += SLOTE * 2;
  bf16* h3    = (bf16*)w; w += SLOTE * 2;
  // ---- zero region ----
  char* zstart = w;
  bf16* extra = (bf16*)w; w += 2 * SLOTE * 2;
  bf16* h2a   = (bf16*)w; w += SLOTE * 2;
  bf16* h2b   = (bf16*)w; w += SLOTE * 2;
  float* ss_li = (float*)w; w += (size_t)(TSTEPS + 1) * BATCH * 4;
  float* ss_bp = (float*)w; w += (size_t)(TSTEPS + 1) * BATCH * 4;
  uint32_t* bar = (uint32_t*)w; w += 17 * 32 * 4;
  int zero_u32 = (int)((w - zstart) / 4);

  cvt_bf16<<<4096, 256, 0, stream>>>(x, xbf, (BATCH * TSTEPS * INDIM) / 4);
  cvt_bf16<<<1024, 256, 0, stream>>>(W_in, winb, (XDIM * INDIM) / 4);
  cvt_bf16<<<32768, 256, 0, stream>>>(W_h, whb, (4 * XDIM * 2 * XDIM) / 4);
  cvt_bf16<<<512, 256, 0, stream>>>(W_out, woutb, (OUTDIM * XDIM) / 4);
  zero32<<<(zero_u32 + 255) / 256, 256, 0, stream>>>((uint32_t*)zstart, zero_u32);
  h0_gemm<<<dim3(16, 128), 256, 0, stream>>>(xbf, winb, b_in, act_ids, h0);

  Params P;
  P.h0 = h0; P.h0m = h0; P.whb = whb; P.b_h = b_h; P.act_ids = act_ids;
  P.h1 = h1; P.h2a = h2a; P.h2b = h2b; P.h3 = h3; P.extra = extra;
  P.ss_li = ss_li; P.ss_bp = ss_bp; P.bar = bar;

  void* kargs[] = {&P};
  hipLaunchCooperativeKernel((const void*)bnn_persistent, dim3(NWG), dim3(512),
                             kargs, 0, stream);

  ybat_gemm<<<dim3(2, TSTEPS), 256, 0, stream>>>(
      extra, h0, woutb, b_out, out_act, out);
}